// Round 1
// baseline (2376.700 us; speedup 1.0000x reference)
//
#include <hip/hip_runtime.h>
#include <hip/hip_bf16.h>

#define N_NODES 50000
#define N_EDGES 1600000
#define F_IN    128
#define F_OUT   8
#define K_TAPS  4
#define MAX_POWER 25   // F_OUT*(K_TAPS-1)+1

// ---------------------------------------------------------------------------
// u[n] = sum_f x[n, f]   (one 64-lane wave per node, float2 loads -> coalesced)
// ---------------------------------------------------------------------------
__global__ void rowsum_kernel(const float* __restrict__ x,
                              float* __restrict__ u, int n_nodes) {
    int wave_in_block = threadIdx.x >> 6;          // 4 waves per 256-thread block
    int lane = threadIdx.x & 63;
    int node = blockIdx.x * 4 + wave_in_block;
    if (node >= n_nodes) return;
    const float2* xp = (const float2*)(x + (size_t)node * F_IN);
    float2 v = xp[lane];                            // 64 lanes * 2 floats = 128
    float s = v.x + v.y;
    #pragma unroll
    for (int off = 32; off > 0; off >>= 1)
        s += __shfl_down(s, off, 64);
    if (lane == 0) u[node] = s;
}

// ---------------------------------------------------------------------------
// dst[rows[e]] += vals[e] * src[cols[e]]   (4 edges/thread, vectorized loads)
// dst must be pre-zeroed.
// ---------------------------------------------------------------------------
__global__ void spmv_kernel(const int4* __restrict__ rows4,
                            const int4* __restrict__ cols4,
                            const float4* __restrict__ vals4,
                            const float* __restrict__ src,
                            float* __restrict__ dst, int n_quads) {
    int q = blockIdx.x * blockDim.x + threadIdx.x;
    if (q >= n_quads) return;
    int4   r = rows4[q];
    int4   c = cols4[q];
    float4 v = vals4[q];
    atomicAdd(&dst[r.x], v.x * src[c.x]);
    atomicAdd(&dst[r.y], v.y * src[c.y]);
    atomicAdd(&dst[r.z], v.z * src[c.z]);
    atomicAdd(&dst[r.w], v.w * src[c.w]);
}

// ---------------------------------------------------------------------------
// y[n, o] = sum_k coeff[o, k] * s[o*(K-1)+k][n]
// s layout: s[p*N + n], p = 0..24 meaning power p+1
// ---------------------------------------------------------------------------
__global__ void combine_kernel(const float* __restrict__ s,
                               const float* __restrict__ coeff,
                               float* __restrict__ y, int n_nodes) {
    int n = blockIdx.x * blockDim.x + threadIdx.x;
    if (n >= n_nodes) return;
    #pragma unroll
    for (int o = 0; o < F_OUT; ++o) {
        float acc = 0.f;
        #pragma unroll
        for (int k = 0; k < K_TAPS; ++k) {
            int p = o * (K_TAPS - 1) + k;           // 0..24
            acc += coeff[o * K_TAPS + k] * s[(size_t)p * n_nodes + n];
        }
        y[(size_t)n * F_OUT + o] = acc;
    }
}

extern "C" void kernel_launch(void* const* d_in, const int* in_sizes, int n_in,
                              void* d_out, int out_size, void* d_ws, size_t ws_size,
                              hipStream_t stream) {
    const float* x        = (const float*)d_in[0];
    const int*   gso_rows = (const int*)d_in[1];
    const int*   gso_cols = (const int*)d_in[2];
    const float* gso_vals = (const float*)d_in[3];
    const float* coeff    = (const float*)d_in[4];
    float* y = (float*)d_out;

    // workspace layout: u (N floats) | s (25 * N floats)
    float* u = (float*)d_ws;
    float* s = u + N_NODES;

    // zero the s buffers (re-poisoned 0xAA before every timed call)
    hipMemsetAsync(s, 0, (size_t)MAX_POWER * N_NODES * sizeof(float), stream);

    // u = rowsum(x)
    rowsum_kernel<<<(N_NODES + 3) / 4, 256, 0, stream>>>(x, u, N_NODES);

    // s_1 = S u ; s_p = S s_{p-1}
    const int n_quads = N_EDGES / 4;
    const int sp_grid = (n_quads + 255) / 256;
    const int4*   rows4 = (const int4*)gso_rows;
    const int4*   cols4 = (const int4*)gso_cols;
    const float4* vals4 = (const float4*)gso_vals;

    spmv_kernel<<<sp_grid, 256, 0, stream>>>(rows4, cols4, vals4, u, s, n_quads);
    for (int p = 1; p < MAX_POWER; ++p) {
        spmv_kernel<<<sp_grid, 256, 0, stream>>>(
            rows4, cols4, vals4,
            s + (size_t)(p - 1) * N_NODES,
            s + (size_t)p * N_NODES, n_quads);
    }

    // y = combine(s, coeff)
    combine_kernel<<<(N_NODES + 255) / 256, 256, 0, stream>>>(s, coeff, y, N_NODES);
}

// Round 2
// 586.228 us; speedup vs baseline: 4.0542x; 4.0542x over previous
//
#include <hip/hip_runtime.h>
#include <hip/hip_bf16.h>

#define N_NODES 50000
#define N_EDGES 1600000
#define F_IN    128
#define F_OUT   8
#define K_TAPS  4
#define MAX_POWER 25   // F_OUT*(K_TAPS-1)+1

// ---------------------------------------------------------------------------
// u[n] = sum_f x[n, f]   (one 64-lane wave per node, float2 loads -> coalesced)
// ---------------------------------------------------------------------------
__global__ void rowsum_kernel(const float* __restrict__ x,
                              float* __restrict__ u, int n_nodes) {
    int wave_in_block = threadIdx.x >> 6;          // 4 waves per 256-thread block
    int lane = threadIdx.x & 63;
    int node = blockIdx.x * 4 + wave_in_block;
    if (node >= n_nodes) return;
    const float2* xp = (const float2*)(x + (size_t)node * F_IN);
    float2 v = xp[lane];                            // 64 lanes * 2 floats = 128
    float s = v.x + v.y;
    #pragma unroll
    for (int off = 32; off > 0; off >>= 1)
        s += __shfl_down(s, off, 64);
    if (lane == 0) u[node] = s;
}

// ---------------------------------------------------------------------------
// CSR build step 1: degree histogram
// ---------------------------------------------------------------------------
__global__ void hist_kernel(const int* __restrict__ rows,
                            int* __restrict__ hist, int n_edges) {
    int i = blockIdx.x * blockDim.x + threadIdx.x;
    if (i < n_edges) atomicAdd(&hist[rows[i]], 1);
}

// ---------------------------------------------------------------------------
// CSR build step 2: exclusive prefix scan of hist -> row_start, cursor
// Single block of 1024 threads; wave-shuffle scan (2 barriers per chunk).
// ---------------------------------------------------------------------------
__device__ inline int wave_incl_scan(int v, int lane) {
    #pragma unroll
    for (int off = 1; off < 64; off <<= 1) {
        int t = __shfl_up(v, off, 64);
        if (lane >= off) v += t;
    }
    return v;
}

__global__ void scan_kernel(const int* __restrict__ hist,
                            int* __restrict__ row_start,
                            int* __restrict__ cursor, int n) {
    __shared__ int wsum[16];
    __shared__ int carry_s;
    int tid = threadIdx.x;
    int lane = tid & 63, wid = tid >> 6;
    if (tid == 0) carry_s = 0;
    __syncthreads();
    for (int base = 0; base < n; base += 1024) {
        int i = base + tid;
        int v = (i < n) ? hist[i] : 0;
        int incl = wave_incl_scan(v, lane);
        if (lane == 63) wsum[wid] = incl;
        __syncthreads();
        if (wid == 0) {
            int w = (lane < 16) ? wsum[lane] : 0;
            w = wave_incl_scan(w, lane);
            if (lane < 16) wsum[lane] = w;
        }
        __syncthreads();
        int wave_off = (wid > 0) ? wsum[wid - 1] : 0;
        int carry = carry_s;
        incl += wave_off;
        int excl = carry + incl - v;
        if (i < n) { row_start[i] = excl; cursor[i] = excl; }
        __syncthreads();
        if (tid == 1023) carry_s = carry + incl;
        __syncthreads();
    }
    if (tid == 0) row_start[n] = carry_s;
}

// ---------------------------------------------------------------------------
// CSR build step 3: scatter edges into row-sorted order
// ---------------------------------------------------------------------------
__global__ void scatter_kernel(const int* __restrict__ rows,
                               const int* __restrict__ cols,
                               const float* __restrict__ vals,
                               int* __restrict__ cursor,
                               int* __restrict__ scol,
                               float* __restrict__ sval, int n_edges) {
    int i = blockIdx.x * blockDim.x + threadIdx.x;
    if (i < n_edges) {
        int pos = atomicAdd(&cursor[rows[i]], 1);
        scol[pos] = cols[i];
        sval[pos] = vals[i];
    }
}

// ---------------------------------------------------------------------------
// Gather SpMV: one wave per row. dst[row] = sum_e sval[e]*src[scol[e]]
// No atomics; src (200 KB) is L2-resident.
// ---------------------------------------------------------------------------
__global__ void spmv_gather_kernel(const int* __restrict__ row_start,
                                   const int* __restrict__ scol,
                                   const float* __restrict__ sval,
                                   const float* __restrict__ src,
                                   float* __restrict__ dst, int n_nodes) {
    int wave_in_block = threadIdx.x >> 6;
    int lane = threadIdx.x & 63;
    int row = blockIdx.x * (blockDim.x >> 6) + wave_in_block;
    if (row >= n_nodes) return;
    int beg = row_start[row];
    int end = row_start[row + 1];
    float acc = 0.f;
    for (int e = beg + lane; e < end; e += 64)
        acc += sval[e] * src[scol[e]];
    #pragma unroll
    for (int off = 32; off > 0; off >>= 1)
        acc += __shfl_down(acc, off, 64);
    if (lane == 0) dst[row] = acc;
}

// ---------------------------------------------------------------------------
// y[n, o] = sum_k coeff[o, k] * s[o*(K-1)+k][n]
// ---------------------------------------------------------------------------
__global__ void combine_kernel(const float* __restrict__ s,
                               const float* __restrict__ coeff,
                               float* __restrict__ y, int n_nodes) {
    int n = blockIdx.x * blockDim.x + threadIdx.x;
    if (n >= n_nodes) return;
    #pragma unroll
    for (int o = 0; o < F_OUT; ++o) {
        float acc = 0.f;
        #pragma unroll
        for (int k = 0; k < K_TAPS; ++k) {
            int p = o * (K_TAPS - 1) + k;           // 0..24
            acc += coeff[o * K_TAPS + k] * s[(size_t)p * n_nodes + n];
        }
        y[(size_t)n * F_OUT + o] = acc;
    }
}

extern "C" void kernel_launch(void* const* d_in, const int* in_sizes, int n_in,
                              void* d_out, int out_size, void* d_ws, size_t ws_size,
                              hipStream_t stream) {
    const float* x        = (const float*)d_in[0];
    const int*   gso_rows = (const int*)d_in[1];
    const int*   gso_cols = (const int*)d_in[2];
    const float* gso_vals = (const float*)d_in[3];
    const float* coeff    = (const float*)d_in[4];
    float* y = (float*)d_out;

    // workspace layout (floats/ints, all 4-byte):
    // u[N] | s[25*N] | hist[N] | row_start[N+1] | cursor[N] | scol[E] | sval[E]
    float* u         = (float*)d_ws;
    float* s         = u + N_NODES;
    int*   hist      = (int*)(s + (size_t)MAX_POWER * N_NODES);
    int*   row_start = hist + N_NODES;
    int*   cursor    = row_start + (N_NODES + 1);
    int*   scol      = cursor + N_NODES;
    float* sval      = (float*)(scol + N_EDGES);

    // --- CSR build (amortized over 25 SpMVs) ---
    hipMemsetAsync(hist, 0, (size_t)N_NODES * sizeof(int), stream);
    hist_kernel<<<(N_EDGES + 255) / 256, 256, 0, stream>>>(gso_rows, hist, N_EDGES);
    scan_kernel<<<1, 1024, 0, stream>>>(hist, row_start, cursor, N_NODES);
    scatter_kernel<<<(N_EDGES + 255) / 256, 256, 0, stream>>>(
        gso_rows, gso_cols, gso_vals, cursor, scol, sval, N_EDGES);

    // --- u = rowsum(x) ---
    rowsum_kernel<<<(N_NODES + 3) / 4, 256, 0, stream>>>(x, u, N_NODES);

    // --- s_1 = S u ; s_p = S s_{p-1} (gather, no atomics) ---
    const int waves_per_block = 4;                  // 256 threads
    const int sp_grid = (N_NODES + waves_per_block - 1) / waves_per_block;
    spmv_gather_kernel<<<sp_grid, 256, 0, stream>>>(row_start, scol, sval, u, s, N_NODES);
    for (int p = 1; p < MAX_POWER; ++p) {
        spmv_gather_kernel<<<sp_grid, 256, 0, stream>>>(
            row_start, scol, sval,
            s + (size_t)(p - 1) * N_NODES,
            s + (size_t)p * N_NODES, N_NODES);
    }

    // --- y = combine(s, coeff) ---
    combine_kernel<<<(N_NODES + 255) / 256, 256, 0, stream>>>(s, coeff, y, N_NODES);
}

// Round 3
// 512.842 us; speedup vs baseline: 4.6344x; 1.1431x over previous
//
#include <hip/hip_runtime.h>
#include <hip/hip_bf16.h>

#define N_NODES 50000
#define N_EDGES 1600000
#define F_IN    128
#define F_OUT   8
#define K_TAPS  4
#define MAX_POWER 25   // F_OUT*(K_TAPS-1)+1

// ---------------------------------------------------------------------------
// u[n] = sum_f x[n, f]   (one 64-lane wave per node, float2 loads -> coalesced)
// ---------------------------------------------------------------------------
__global__ void rowsum_kernel(const float* __restrict__ x,
                              float* __restrict__ u, int n_nodes) {
    int wave_in_block = threadIdx.x >> 6;
    int lane = threadIdx.x & 63;
    int node = blockIdx.x * 4 + wave_in_block;
    if (node >= n_nodes) return;
    const float2* xp = (const float2*)(x + (size_t)node * F_IN);
    float2 v = xp[lane];
    float s = v.x + v.y;
    #pragma unroll
    for (int off = 32; off > 0; off >>= 1)
        s += __shfl_down(s, off, 64);
    if (lane == 0) u[node] = s;
}

// ---------------------------------------------------------------------------
// CSR step 1: degree histogram (int4-vectorized edge reads)
// ---------------------------------------------------------------------------
__global__ void hist_kernel(const int4* __restrict__ rows4,
                            int* __restrict__ hist, int n_quads) {
    int q = blockIdx.x * blockDim.x + threadIdx.x;
    if (q >= n_quads) return;
    int4 r = rows4[q];
    atomicAdd(&hist[r.x], 1);
    atomicAdd(&hist[r.y], 1);
    atomicAdd(&hist[r.z], 1);
    atomicAdd(&hist[r.w], 1);
}

// ---------------------------------------------------------------------------
// CSR step 2: hierarchical exclusive scan (3 tiny kernels)
// ---------------------------------------------------------------------------
__device__ inline int wave_incl_scan(int v, int lane) {
    #pragma unroll
    for (int off = 1; off < 64; off <<= 1) {
        int t = __shfl_up(v, off, 64);
        if (lane >= off) v += t;
    }
    return v;
}

// per-block (1024 elems) exclusive scan + block total
__global__ void scan_block_kernel(const int* __restrict__ hist,
                                  int* __restrict__ excl,
                                  int* __restrict__ partials, int n) {
    __shared__ int wsum[4];
    int tid = threadIdx.x;
    int base = blockIdx.x * 1024 + tid * 4;
    int4 v = make_int4(0, 0, 0, 0);
    if (base + 3 < n) v = *(const int4*)(hist + base);
    else {
        if (base     < n) v.x = hist[base];
        if (base + 1 < n) v.y = hist[base + 1];
        if (base + 2 < n) v.z = hist[base + 2];
        if (base + 3 < n) v.w = hist[base + 3];
    }
    int tsum = v.x + v.y + v.z + v.w;
    int lane = tid & 63, wid = tid >> 6;
    int incl = wave_incl_scan(tsum, lane);
    if (lane == 63) wsum[wid] = incl;
    __syncthreads();
    int woff = 0;
    for (int w = 0; w < wid; ++w) woff += wsum[w];
    int e0 = woff + incl - tsum;
    int e1 = e0 + v.x, e2 = e1 + v.y, e3 = e2 + v.z;
    if (base     < n) excl[base]     = e0;
    if (base + 1 < n) excl[base + 1] = e1;
    if (base + 2 < n) excl[base + 2] = e2;
    if (base + 3 < n) excl[base + 3] = e3;
    if (tid == 0)
        partials[blockIdx.x] = wsum[0] + wsum[1] + wsum[2] + wsum[3];
}

// scan the (<=64) block partials with one wave
__global__ void scan_partials_kernel(const int* __restrict__ partials,
                                     int* __restrict__ offs, int nb) {
    int lane = threadIdx.x;
    int v = (lane < nb) ? partials[lane] : 0;
    int incl = wave_incl_scan(v, lane);
    if (lane < nb) offs[lane] = incl - v;
}

// add block offsets, materialize row_start + cursor
__global__ void scan_add_kernel(const int* __restrict__ excl,
                                const int* __restrict__ offs,
                                int* __restrict__ row_start,
                                int* __restrict__ cursor, int n) {
    int i = blockIdx.x * blockDim.x + threadIdx.x;
    if (i < n) {
        int v = excl[i] + offs[i >> 10];
        row_start[i] = v;
        cursor[i] = v;
    }
    if (i == 0) row_start[n] = N_EDGES;
}

// ---------------------------------------------------------------------------
// CSR step 3: scatter edges, (col,val) interleaved -> one 8B store per edge
// ---------------------------------------------------------------------------
__global__ void scatter_kernel(const int4* __restrict__ rows4,
                               const int4* __restrict__ cols4,
                               const float4* __restrict__ vals4,
                               int* __restrict__ cursor,
                               int2* __restrict__ edges, int n_quads) {
    int q = blockIdx.x * blockDim.x + threadIdx.x;
    if (q >= n_quads) return;
    int4   r = rows4[q];
    int4   c = cols4[q];
    float4 v = vals4[q];
    int p;
    p = atomicAdd(&cursor[r.x], 1); edges[p] = make_int2(c.x, __float_as_int(v.x));
    p = atomicAdd(&cursor[r.y], 1); edges[p] = make_int2(c.y, __float_as_int(v.y));
    p = atomicAdd(&cursor[r.z], 1); edges[p] = make_int2(c.z, __float_as_int(v.z));
    p = atomicAdd(&cursor[r.w], 1); edges[p] = make_int2(c.w, __float_as_int(v.w));
}

// ---------------------------------------------------------------------------
// Gather SpMV: 2 rows per wave (32 lanes each, avg degree 32). No atomics.
// ---------------------------------------------------------------------------
__global__ void spmv_gather_kernel(const int* __restrict__ row_start,
                                   const int2* __restrict__ edges,
                                   const float* __restrict__ src,
                                   float* __restrict__ dst, int n_nodes) {
    int tid = threadIdx.x;
    int lane = tid & 63;
    int half = lane >> 5;                 // 0 or 1
    int sub  = lane & 31;
    int wave = (blockIdx.x * blockDim.x + tid) >> 6;
    int row = wave * 2 + half;
    if (row >= n_nodes) return;
    int beg = row_start[row];
    int end = row_start[row + 1];
    float acc = 0.f;
    for (int e = beg + sub; e < end; e += 32) {
        int2 ev = edges[e];
        acc += __int_as_float(ev.y) * src[ev.x];
    }
    #pragma unroll
    for (int off = 16; off > 0; off >>= 1)
        acc += __shfl_down(acc, off, 32);
    if (sub == 0) dst[row] = acc;
}

// ---------------------------------------------------------------------------
// y[n, o] = sum_k coeff[o, k] * s[o*(K-1)+k][n]
// ---------------------------------------------------------------------------
__global__ void combine_kernel(const float* __restrict__ s,
                               const float* __restrict__ coeff,
                               float* __restrict__ y, int n_nodes) {
    int n = blockIdx.x * blockDim.x + threadIdx.x;
    if (n >= n_nodes) return;
    #pragma unroll
    for (int o = 0; o < F_OUT; ++o) {
        float acc = 0.f;
        #pragma unroll
        for (int k = 0; k < K_TAPS; ++k) {
            int p = o * (K_TAPS - 1) + k;
            acc += coeff[o * K_TAPS + k] * s[(size_t)p * n_nodes + n];
        }
        y[(size_t)n * F_OUT + o] = acc;
    }
}

extern "C" void kernel_launch(void* const* d_in, const int* in_sizes, int n_in,
                              void* d_out, int out_size, void* d_ws, size_t ws_size,
                              hipStream_t stream) {
    const float* x        = (const float*)d_in[0];
    const int*   gso_rows = (const int*)d_in[1];
    const int*   gso_cols = (const int*)d_in[2];
    const float* gso_vals = (const float*)d_in[3];
    const float* coeff    = (const float*)d_in[4];
    float* y = (float*)d_out;

    // ws layout (4-byte units, 8B-alignment of edges maintained):
    // u[N] | s[25N] | hist[N] | excl[N] | partials[64] | offs[64]
    //   | row_start[N+2 pad] | cursor[N] | edges[2E]
    float* u         = (float*)d_ws;
    float* s         = u + N_NODES;
    int*   hist      = (int*)(s + (size_t)MAX_POWER * N_NODES);
    int*   excl      = hist + N_NODES;
    int*   partials  = excl + N_NODES;
    int*   offs      = partials + 64;
    int*   row_start = offs + 64;
    int*   cursor    = row_start + (N_NODES + 2);   // +2 keeps edges 8B-aligned
    int2*  edges     = (int2*)(cursor + N_NODES);

    const int n_quads = N_EDGES / 4;
    const int nb = (N_NODES + 1023) / 1024;         // 49 scan blocks

    // --- CSR build ---
    hipMemsetAsync(hist, 0, (size_t)N_NODES * sizeof(int), stream);
    hist_kernel<<<(n_quads + 255) / 256, 256, 0, stream>>>(
        (const int4*)gso_rows, hist, n_quads);
    scan_block_kernel<<<nb, 256, 0, stream>>>(hist, excl, partials, N_NODES);
    scan_partials_kernel<<<1, 64, 0, stream>>>(partials, offs, nb);
    scan_add_kernel<<<(N_NODES + 255) / 256, 256, 0, stream>>>(
        excl, offs, row_start, cursor, N_NODES);
    scatter_kernel<<<(n_quads + 255) / 256, 256, 0, stream>>>(
        (const int4*)gso_rows, (const int4*)gso_cols, (const float4*)gso_vals,
        cursor, edges, n_quads);

    // --- u = rowsum(x) ---
    rowsum_kernel<<<(N_NODES + 3) / 4, 256, 0, stream>>>(x, u, N_NODES);

    // --- s_1 = S u ; s_p = S s_{p-1} ---
    const int rows_per_block = 8;                   // 4 waves * 2 rows
    const int sp_grid = (N_NODES + rows_per_block - 1) / rows_per_block;
    spmv_gather_kernel<<<sp_grid, 256, 0, stream>>>(row_start, edges, u, s, N_NODES);
    for (int p = 1; p < MAX_POWER; ++p) {
        spmv_gather_kernel<<<sp_grid, 256, 0, stream>>>(
            row_start, edges,
            s + (size_t)(p - 1) * N_NODES,
            s + (size_t)p * N_NODES, N_NODES);
    }

    // --- y = combine(s, coeff) ---
    combine_kernel<<<(N_NODES + 255) / 256, 256, 0, stream>>>(s, coeff, y, N_NODES);
}

// Round 4
// 454.275 us; speedup vs baseline: 5.2318x; 1.1289x over previous
//
#include <hip/hip_runtime.h>
#include <hip/hip_bf16.h>

#define N_NODES 50000
#define N_EDGES 1600000
#define F_IN    128
#define F_OUT   8
#define K_TAPS  4
#define MAX_POWER 25     // F_OUT*(K_TAPS-1)+1

#define BROWS   64       // rows per bucket
#define NB      782      // ceil(N_NODES / BROWS)
#define CHUNK   4096     // edges per partition block
#define NPART   391      // ceil(N_EDGES / CHUNK)

__device__ inline int wave_incl_scan(int v, int lane) {
    #pragma unroll
    for (int off = 1; off < 64; off <<= 1) {
        int t = __shfl_up(v, off, 64);
        if (lane >= off) v += t;
    }
    return v;
}

// ---------------------------------------------------------------------------
// u[n] = sum_f x[n, f]   (one 64-lane wave per node, float2 loads)
// ---------------------------------------------------------------------------
__global__ void rowsum_kernel(const float* __restrict__ x,
                              float* __restrict__ u, int n_nodes) {
    int wave_in_block = threadIdx.x >> 6;
    int lane = threadIdx.x & 63;
    int node = blockIdx.x * 4 + wave_in_block;
    if (node >= n_nodes) return;
    const float2* xp = (const float2*)(x + (size_t)node * F_IN);
    float2 v = xp[lane];
    float s = v.x + v.y;
    #pragma unroll
    for (int off = 32; off > 0; off >>= 1)
        s += __shfl_down(s, off, 64);
    if (lane == 0) u[node] = s;
}

// ---------------------------------------------------------------------------
// Bucket histogram: per-block LDS hist, one global atomic per (block,bucket)
// ---------------------------------------------------------------------------
__global__ void ghist_kernel(const int4* __restrict__ rows4,
                             int* __restrict__ ghist, int n_quads) {
    __shared__ int lh[NB];
    int tid = threadIdx.x;
    for (int b = tid; b < NB; b += 256) lh[b] = 0;
    __syncthreads();
    int qbeg = blockIdx.x * (CHUNK / 4);
    int qend = min(qbeg + CHUNK / 4, n_quads);
    for (int q = qbeg + tid; q < qend; q += 256) {
        int4 r = rows4[q];
        atomicAdd(&lh[r.x >> 6], 1);
        atomicAdd(&lh[r.y >> 6], 1);
        atomicAdd(&lh[r.z >> 6], 1);
        atomicAdd(&lh[r.w >> 6], 1);
    }
    __syncthreads();
    for (int b = tid; b < NB; b += 256) {
        int c = lh[b];
        if (c) atomicAdd(&ghist[b], c);
    }
}

// ---------------------------------------------------------------------------
// Exclusive scan of 782 bucket counts (single block)
// ---------------------------------------------------------------------------
__global__ void bucket_scan_kernel(const int* __restrict__ ghist,
                                   int* __restrict__ bucket_start,
                                   int* __restrict__ bucket_cursor) {
    __shared__ int wsum[4];
    int tid = threadIdx.x, lane = tid & 63, wid = tid >> 6;
    int b0 = tid * 4;
    int h[4]; int tsum = 0;
    #pragma unroll
    for (int j = 0; j < 4; ++j) {
        h[j] = (b0 + j < NB) ? ghist[b0 + j] : 0;
        tsum += h[j];
    }
    int incl = wave_incl_scan(tsum, lane);
    if (lane == 63) wsum[wid] = incl;
    __syncthreads();
    int woff = 0;
    for (int w = 0; w < wid; ++w) woff += wsum[w];
    int excl = woff + incl - tsum;
    #pragma unroll
    for (int j = 0; j < 4; ++j) {
        if (b0 + j < NB) { bucket_start[b0 + j] = excl; bucket_cursor[b0 + j] = excl; }
        excl += h[j];
    }
    if (tid == 255) bucket_start[NB] = woff + incl;   // == N_EDGES
}

// ---------------------------------------------------------------------------
// Partition edges into buckets with LDS staging (coalesced run writes).
// Payload: int2( (local_row<<16) | col , bits(val) )
// ---------------------------------------------------------------------------
__global__ void partition_kernel(const int* __restrict__ rows,
                                 const int* __restrict__ cols,
                                 const float* __restrict__ vals,
                                 int* __restrict__ bucket_cursor,
                                 int2* __restrict__ edges, int n_edges) {
    __shared__ int lhist[NB];
    __shared__ int lcur[NB];
    __shared__ int lbase[NB];
    __shared__ int2 stage[CHUNK];
    __shared__ unsigned short sbkt[CHUNK];
    __shared__ int wsum[4];
    int tid = threadIdx.x;
    int base = blockIdx.x * CHUNK;
    int cend = min(base + CHUNK, n_edges);

    for (int b = tid; b < NB; b += 256) lhist[b] = 0;
    __syncthreads();
    for (int i = base + tid; i < cend; i += 256)
        atomicAdd(&lhist[rows[i] >> 6], 1);
    __syncthreads();

    // exclusive scan of lhist -> lcur
    int lane = tid & 63, wid = tid >> 6;
    int b0 = tid * 4;
    int h[4]; int tsum = 0;
    #pragma unroll
    for (int j = 0; j < 4; ++j) {
        h[j] = (b0 + j < NB) ? lhist[b0 + j] : 0;
        tsum += h[j];
    }
    int incl = wave_incl_scan(tsum, lane);
    if (lane == 63) wsum[wid] = incl;
    __syncthreads();
    int woff = 0;
    for (int w = 0; w < wid; ++w) woff += wsum[w];
    int excl = woff + incl - tsum;
    #pragma unroll
    for (int j = 0; j < 4; ++j) {
        if (b0 + j < NB) lcur[b0 + j] = excl;
        excl += h[j];
    }
    __syncthreads();

    // reserve global space per non-empty bucket
    for (int b = tid; b < NB; b += 256) {
        int c = lhist[b];
        if (c) {
            int g = atomicAdd(&bucket_cursor[b], c);
            lbase[b] = g - lcur[b];
        }
    }
    __syncthreads();

    // stage edges sorted-by-bucket in LDS
    for (int i = base + tid; i < cend; i += 256) {
        int r = rows[i], c = cols[i];
        float v = vals[i];
        int b = r >> 6;
        int pos = atomicAdd(&lcur[b], 1);
        stage[pos] = make_int2(((r & 63) << 16) | c, __float_as_int(v));
        sbkt[pos] = (unsigned short)b;
    }
    __syncthreads();

    // write out: consecutive staged slots -> consecutive global slots per run
    int cn = cend - base;
    for (int i = tid; i < cn; i += 256) {
        int b = sbkt[i];
        edges[lbase[b] + i] = stage[i];
    }
}

// ---------------------------------------------------------------------------
// SpMV: one block per bucket, LDS fp32 atomic accumulation over 64 rows.
// Edges need only be bucket-grouped, not row-sorted.
// ---------------------------------------------------------------------------
__global__ void spmv_bucket_kernel(const int* __restrict__ bucket_start,
                                   const int2* __restrict__ edges,
                                   const float* __restrict__ src,
                                   float* __restrict__ dst, int n_nodes) {
    __shared__ float acc[BROWS];
    int tid = threadIdx.x;
    if (tid < BROWS) acc[tid] = 0.f;
    __syncthreads();
    int b = blockIdx.x;
    int beg = bucket_start[b], end = bucket_start[b + 1];
    for (int e = beg + tid; e < end; e += 256) {
        int2 ev = edges[e];
        atomicAdd(&acc[ev.x >> 16], __int_as_float(ev.y) * src[ev.x & 0xFFFF]);
    }
    __syncthreads();
    int row = b * BROWS + tid;
    if (tid < BROWS && row < n_nodes) dst[row] = acc[tid];
}

// ---------------------------------------------------------------------------
// y[n, o] = sum_k coeff[o, k] * s[o*(K-1)+k][n]
// ---------------------------------------------------------------------------
__global__ void combine_kernel(const float* __restrict__ s,
                               const float* __restrict__ coeff,
                               float* __restrict__ y, int n_nodes) {
    int n = blockIdx.x * blockDim.x + threadIdx.x;
    if (n >= n_nodes) return;
    #pragma unroll
    for (int o = 0; o < F_OUT; ++o) {
        float acc = 0.f;
        #pragma unroll
        for (int k = 0; k < K_TAPS; ++k) {
            int p = o * (K_TAPS - 1) + k;
            acc += coeff[o * K_TAPS + k] * s[(size_t)p * n_nodes + n];
        }
        y[(size_t)n * F_OUT + o] = acc;
    }
}

extern "C" void kernel_launch(void* const* d_in, const int* in_sizes, int n_in,
                              void* d_out, int out_size, void* d_ws, size_t ws_size,
                              hipStream_t stream) {
    const float* x        = (const float*)d_in[0];
    const int*   gso_rows = (const int*)d_in[1];
    const int*   gso_cols = (const int*)d_in[2];
    const float* gso_vals = (const float*)d_in[3];
    const float* coeff    = (const float*)d_in[4];
    float* y = (float*)d_out;

    // ws layout: u[N] | s[25N] | edges[E] (int2, 8B-aligned) | ghist[NB]
    //            | bucket_start[NB+1] | bucket_cursor[NB]
    float* u      = (float*)d_ws;
    float* s      = u + N_NODES;                       // 50000+1250000 floats -> 8B-aligned end
    int2*  edges  = (int2*)(s + (size_t)MAX_POWER * N_NODES);
    int*   ghist  = (int*)(edges + N_EDGES);
    int*   bucket_start  = ghist + NB;
    int*   bucket_cursor = bucket_start + (NB + 1);

    const int n_quads = N_EDGES / 4;

    // --- bucket CSR build ---
    hipMemsetAsync(ghist, 0, NB * sizeof(int), stream);
    ghist_kernel<<<NPART, 256, 0, stream>>>((const int4*)gso_rows, ghist, n_quads);
    bucket_scan_kernel<<<1, 256, 0, stream>>>(ghist, bucket_start, bucket_cursor);
    partition_kernel<<<NPART, 256, 0, stream>>>(
        gso_rows, gso_cols, gso_vals, bucket_cursor, edges, N_EDGES);

    // --- u = rowsum(x) ---
    rowsum_kernel<<<(N_NODES + 3) / 4, 256, 0, stream>>>(x, u, N_NODES);

    // --- s_1 = S u ; s_p = S s_{p-1} ---
    spmv_bucket_kernel<<<NB, 256, 0, stream>>>(bucket_start, edges, u, s, N_NODES);
    for (int p = 1; p < MAX_POWER; ++p) {
        spmv_bucket_kernel<<<NB, 256, 0, stream>>>(
            bucket_start, edges,
            s + (size_t)(p - 1) * N_NODES,
            s + (size_t)p * N_NODES, N_NODES);
    }

    // --- y = combine(s, coeff) ---
    combine_kernel<<<(N_NODES + 255) / 256, 256, 0, stream>>>(s, coeff, y, N_NODES);
}